// Round 18
// baseline (183.374 us; speedup 1.0000x reference)
//
#include <hip/hip_runtime.h>
#include <hip/hip_bf16.h>
#include <math.h>

#define EMB 64
#define CAPB 3584      // per-bucket slot capacity (mean 3125, sigma ~56 -> 8.2 sigma)
#define CHUNK 4096     // edges per bin block

typedef __attribute__((ext_vector_type(8))) short bf16x8;
typedef __attribute__((ext_vector_type(4))) float f32x4;

__device__ __forceinline__ ushort bf16_rne(float f) {
    uint u = __float_as_uint(f);
    return (ushort)((u + 0x7fffu + ((u >> 16) & 1u)) >> 16);
}

__device__ __forceinline__ uint bf16_pack2(float a, float b) {
    return (uint)bf16_rne(a) | ((uint)bf16_rne(b) << 16);
}

// ---------------- prep kernel: bin(U) | bin(I) | cast_bf16 | pack W ----------------
// gcur assumed zeroed (hipMemsetAsync). Record: int2(col | inrow<<17, f32val).
// Binned writes are LDS-staged in bucket-sorted order -> coalesced full-line runs.

__device__ __forceinline__ void bin_body(
    const int* __restrict__ rows, const int* __restrict__ cols,
    const float* __restrict__ vals, int nE, int B, int RPB,
    int* gcur, int2* __restrict__ binned, int blk,
    int* cnt, int* sstart, int* lbase, int2* rec, ushort* bkt) {
    int t = threadIdx.x;
    for (int i = t; i < B; i += 256) cnt[i] = 0;
    __syncthreads();
    int c0 = blk * CHUNK;
    int ntot = nE - c0; if (ntot > CHUNK) ntot = CHUNK;
    int bs[16];
#pragma unroll
    for (int j = 0; j < 16; ++j) {
        int idx = c0 + t + j * 256;
        int bsv = -1;
        if (idx < nE) {
            int row = rows[idx];
            int b = row / RPB;
            int inrow = row - b * RPB;
            int slot = atomicAdd(&cnt[b], 1);
            bsv = (b << 21) | (inrow << 13) | slot;   // b<512, inrow<256, slot<8192
        }
        bs[j] = bsv;
    }
    __syncthreads();
    // reserve global runs per bucket
    for (int i = t; i < B; i += 256) {
        int c = cnt[i];
        lbase[i] = c ? atomicAdd(&gcur[i * 16], c) : 0;
    }
    // exclusive scan of cnt -> sstart (wave 0, B/64 segments with carry)
    if (t < 64) {
        int carry = 0;
        int nseg = B >> 6;
        for (int seg = 0; seg < nseg; ++seg) {
            int i = seg * 64 + t;
            int v = cnt[i];
            int s = v;
#pragma unroll
            for (int d = 1; d < 64; d <<= 1) {
                int u2 = __shfl_up(s, d);
                if (t >= d) s += u2;
            }
            sstart[i] = carry + s - v;
            carry += __shfl(s, 63);
        }
    }
    __syncthreads();
    // stage records into LDS in bucket-sorted order
#pragma unroll
    for (int j = 0; j < 16; ++j) {
        int idx = c0 + t + j * 256;
        if (idx >= nE) continue;
        int bsv = bs[j];
        int b = bsv >> 21, inrow = (bsv >> 13) & 0xFF, slot = bsv & 0x1FFF;
        int col = cols[idx];
        float v = vals[idx];
        int li = sstart[b] + slot;
        rec[li] = make_int2(col | (inrow << 17), __float_as_int(v));
        bkt[li] = (ushort)b;
    }
    __syncthreads();
    // coalesced copy: consecutive i in a bucket -> consecutive global dest
    for (int i = t; i < ntot; i += 256) {
        int b = bkt[i];
        int pos = lbase[b] + (i - sstart[b]);
        if (pos < CAPB)
            binned[(size_t)b * CAPB + pos] = rec[i];
    }
}

__global__ __launch_bounds__(256) void prep(
    const int* __restrict__ u_rows, const int* __restrict__ u_cols,
    const float* __restrict__ u_vals, int eu, int BU, int RPBU,
    int* gcurU, int2* __restrict__ binnedU, int nbU,
    const int* __restrict__ i_rows, const int* __restrict__ i_cols,
    const float* __restrict__ i_vals, int ei, int BI, int RPBI,
    int* gcurI, int2* __restrict__ binnedI, int nbI,
    const float4* __restrict__ embU, ushort* __restrict__ xbU, long n4u,
    const float4* __restrict__ embI, ushort* __restrict__ xbI, long n4i,
    int nbCast,
    const float4* __restrict__ W0s, ushort* __restrict__ W0d,
    const float4* __restrict__ W1s, ushort* __restrict__ W1d,
    const float4* __restrict__ W2s, ushort* __restrict__ W2d,
    const float4* __restrict__ W3s, ushort* __restrict__ W3d) {
    __shared__ int2 rec[CHUNK];        // 32 KB
    __shared__ ushort bkt[CHUNK];      // 8 KB
    __shared__ int cnt[512];
    __shared__ int sstart[512];
    __shared__ int lbase[512];
    int b = blockIdx.x;
    if (b < nbU) {
        bin_body(u_rows, u_cols, u_vals, eu, BU, RPBU, gcurU, binnedU, b,
                 cnt, sstart, lbase, rec, bkt);
        return;
    }
    b -= nbU;
    if (b < nbI) {
        bin_body(i_rows, i_cols, i_vals, ei, BI, RPBI, gcurI, binnedI, b,
                 cnt, sstart, lbase, rec, bkt);
        return;
    }
    b -= nbI;
    if (b < nbCast) {
        // cast: 4 float4 per thread, strided
        long tot = n4u + n4i;
        long base = (long)b * 1024 + threadIdx.x;
#pragma unroll
        for (int k = 0; k < 4; ++k) {
            long i = base + k * 256;
            if (i >= tot) return;
            const float4* a; ushort* o; long j;
            if (i < n4u) { a = embU; o = xbU; j = i; }
            else { a = embI; o = xbI; j = i - n4u; }
            float4 v = a[j];
            ushort4 r;
            r.x = bf16_rne(v.x); r.y = bf16_rne(v.y); r.z = bf16_rne(v.z); r.w = bf16_rne(v.w);
            *(ushort4*)(o + j * 4) = r;
        }
        return;
    }
    b -= nbCast;
    // pack one 64x64 W matrix to bf16 (16 contiguous elems per thread)
    {
        const float4* src = (b == 0) ? W0s : (b == 1) ? W1s : (b == 2) ? W2s : W3s;
        ushort* dst = (b == 0) ? W0d : (b == 1) ? W1d : (b == 2) ? W2d : W3d;
        int t = threadIdx.x;
        float4 v0 = src[t * 4 + 0], v1 = src[t * 4 + 1];
        float4 v2 = src[t * 4 + 2], v3 = src[t * 4 + 3];
        uint4 o0, o1;
        o0.x = bf16_pack2(v0.x, v0.y); o0.y = bf16_pack2(v0.z, v0.w);
        o0.z = bf16_pack2(v1.x, v1.y); o0.w = bf16_pack2(v1.z, v1.w);
        o1.x = bf16_pack2(v2.x, v2.y); o1.y = bf16_pack2(v2.z, v2.w);
        o1.z = bf16_pack2(v3.x, v3.y); o1.w = bf16_pack2(v3.z, v3.w);
        ((uint4*)dst)[t * 2 + 0] = o0;
        ((uint4*)dst)[t * 2 + 1] = o1;
    }
}

// ---------------- finalize: bucket sort -> packed 4B CSR records ----------------
// One workgroup per bucket. Row-sorts its records and emits 4-byte packed records:
//   uint( col[16:0] | bf16_sans_sign(val)[31:17] )   (vals are >= 0)
// plus per-row int2(start,end) offsets (uint indices into ccvp).

__global__ __launch_bounds__(256) void finalize_csr(
    const int2* __restrict__ binnedU, const int* __restrict__ gcurU, int RPBU, int nu,
    uint* __restrict__ ccvpU, int2* __restrict__ offseU, int BU,
    const int2* __restrict__ binnedI, const int* __restrict__ gcurI, int RPBI, int ni,
    uint* __restrict__ ccvpI, int2* __restrict__ offseI) {
    __shared__ int2 rec[CAPB];
    __shared__ int cnt_r[256];
    __shared__ int excl[257];
    __shared__ int curs[256];
    int b = blockIdx.x;
    const int2* binned; const int* gcur; int RPB; int n; uint* ccvp; int2* offse;
    if (b < BU) {
        binned = binnedU; gcur = gcurU; RPB = RPBU; n = nu; ccvp = ccvpU; offse = offseU;
    } else {
        b -= BU;
        binned = binnedI; gcur = gcurI; RPB = RPBI; n = ni; ccvp = ccvpI; offse = offseI;
    }
    int t = threadIdx.x;
    int r0 = b * RPB;
    int nrows = n - r0; if (nrows > RPB) nrows = RPB;
    if (nrows <= 0) return;
    int cnt = gcur[b * 16];
    if (cnt > CAPB) cnt = CAPB;
    const int2* src = binned + (size_t)b * CAPB;
    int B0 = b * CAPB;
    cnt_r[t] = 0;
    __syncthreads();
    for (int p = t; p < cnt; p += 256) {
        int2 r = src[p];
        rec[p] = r;
        atomicAdd(&cnt_r[(r.x >> 17) & 0xFF], 1);
    }
    __syncthreads();
    // exclusive scan of 256 counters: wave 0, 4 segments of 64 with carry
    if (t < 64) {
        int carry = 0;
#pragma unroll
        for (int seg = 0; seg < 4; ++seg) {
            int i = seg * 64 + t;
            int v = cnt_r[i];
            int s = v;
#pragma unroll
            for (int d = 1; d < 64; d <<= 1) {
                int u2 = __shfl_up(s, d);
                if (t >= d) s += u2;
            }
            excl[i] = carry + s - v;
            carry += __shfl(s, 63);
        }
        if (t == 0) excl[256] = carry;
    }
    __syncthreads();
    curs[t] = excl[t];
    if (t < nrows) offse[r0 + t] = make_int2(B0 + excl[t], B0 + excl[t + 1]);
    __syncthreads();
    for (int p = t; p < cnt; p += 256) {
        int2 r = rec[p];
        int inrow = (r.x >> 17) & 0xFF;
        int slot = atomicAdd(&curs[inrow], 1);
        float v = __int_as_float(r.y);                     // v >= 0
        uint v15 = ((uint)bf16_rne(v)) & 0x7FFFu;          // bf16 without sign bit
        ccvp[B0 + slot] = (uint)(r.x & 0x1FFFF) | (v15 << 17);
    }
}

// ---------------- fused SPMM + MFMA dense + leaky_relu + L2 norm ----------------
// ONE 64-row tile per block (grid = ntU + ntI). Block = 4 waves; wave owns 16 rows
// in 4 passes of 4 rows; each 16-lane group owns ONE row per pass with an 8-deep
// edge batch + cross-batch record prefetch (r17). NON-TEMPORAL record loads and
// y stores: records (9.6MB) and outputs (9.6-38MB) are touched once with zero
// reuse — keeping them out of L2 preserves capacity for the x gather working set
// (19.2MB vs 4MB/XCD L2). r16 evidence: streaming-bytes reduction is the only
// lever that has moved spmm (L2-capacity mechanism, FETCH unchanged).
// Edge record 4B packed: col[16:0] | bf16_sans_sign(val)[31:17]. W pre-packed
// bf16 in global. Dense: X(16x64)@W^T via 8x mfma_f32_16x16x32_bf16. C/D layout
// (verified): col=lane&15, row=(lane>>4)*4+reg. Norm: 4-step shfl_xor butterfly.
// x and y MUST be distinct buffers. launch_bounds(256,4): ~70 VGPR, no spill.

__global__ __launch_bounds__(256, 4) void spmm_mfma(
    const int2* __restrict__ offseU, const uint* __restrict__ ccvU,
    const ushort* __restrict__ xu, const ushort* __restrict__ Wu, const float* __restrict__ bu,
    float* __restrict__ yfu, ushort* __restrict__ ybu, int nu, int ntU,
    const int2* __restrict__ offseI, const uint* __restrict__ ccvI,
    const ushort* __restrict__ xi, const ushort* __restrict__ Wi, const float* __restrict__ bi,
    float* __restrict__ yfi, ushort* __restrict__ ybi, int ni) {
    __shared__ ushort wt[64 * 72];       // W row-major bf16, rows padded to 72
    __shared__ ushort xt[4 * 16 * 72];   // per-wave X tiles
    int tid = threadIdx.x;
    int lane = tid & 63, wid = tid >> 6;
    int q = lane & 15, g = lane >> 4;
    int tile = blockIdx.x;
    const int2* offse; const uint* ccv; const ushort* x; const ushort* W; const float* bv;
    float* yf; ushort* yb; int n;
    if (tile < ntU) {
        offse = offseU; ccv = ccvU; x = xu; W = Wu; bv = bu; yf = yfu; yb = ybu; n = nu;
    } else {
        tile -= ntU;
        offse = offseI; ccv = ccvI; x = xi; W = Wi; bv = bi; yf = yfi; yb = ybi; n = ni;
    }
    // stage W: thread t copies elements [t*16, t*16+16) -> row r=t/4, col (t%4)*16
    {
        int r = tid >> 2, c = (tid & 3) * 16;
        uint4 v0 = ((const uint4*)W)[tid * 2 + 0];
        uint4 v1 = ((const uint4*)W)[tid * 2 + 1];
        *(uint4*)(wt + r * 72 + c) = v0;
        *(uint4*)(wt + r * 72 + c + 8) = v1;
    }
    float bias[4];
#pragma unroll
    for (int t = 0; t < 4; ++t) bias[t] = bv[16 * t + q];
    __syncthreads();

    const uint2* xv2 = (const uint2*)x;
    ushort* xw = xt + wid * (16 * 72);
    int rowW = (tile << 6) + wid * 16;   // wave's first row

    // ---- preload the wave's 16 rows' offse: one coalesced 128B load ----
    int2 se = make_int2(0, 0);
    {
        int r16 = rowW + lane;
        if (lane < 16 && r16 < n) se = offse[r16];
    }
    int Sa[4], Ea[4];
#pragma unroll
    for (int j = 0; j < 4; ++j) {
        Sa[j] = __shfl(se.x, j * 4 + g);
        Ea[j] = __shfl(se.y, j * 4 + g);
    }

    // ---- pipelined gather: prefetch next batch's records during current gathers ----
    uint edC[8], edN[8];
    {   // prologue: records for (row 0, first batch)
        int sn = Sa[0], en = Ea[0];
        int safe = (en > sn) ? en - 1 : 0;
#pragma unroll
        for (int k = 0; k < 8; ++k) {
            int ii = sn + k;
            edC[k] = __builtin_nontemporal_load(ccv + ((ii < en) ? ii : safe));
        }
    }
#pragma unroll
    for (int j = 0; j < 4; ++j) {
        int s = Sa[j], e = Ea[j];
        int sN = (j < 3) ? Sa[j + 1] : 0;
        int eN = (j < 3) ? Ea[j + 1] : 0;
        float av[4] = {0.f, 0.f, 0.f, 0.f};
        int nb = (e - s + 7) >> 3; if (nb < 1) nb = 1;
        int p = s;
        for (int b = 0; b < nb; ++b, p += 8) {
            bool lastb = (b + 1 >= nb);
            int pn = lastb ? sN : (p + 8);
            int en = lastb ? eN : e;
            int sn = lastb ? sN : s;
            // gathers for current batch (records already resident)
            uint2 gx[8];
#pragma unroll
            for (int k = 0; k < 8; ++k)
                gx[k] = xv2[(size_t)(edC[k] & 0x1FFFFu) * 16 + q];
            // prefetch next batch's records (independent of gathers)
            int safeN = (en > sn) ? en - 1 : 0;
#pragma unroll
            for (int k = 0; k < 8; ++k) {
                int ii = pn + k;
                edN[k] = __builtin_nontemporal_load(ccv + ((ii < en) ? ii : safeN));
            }
            // accumulate
#pragma unroll
            for (int k = 0; k < 8; ++k) {
                float v = (p + k < e) ? __uint_as_float((edC[k] >> 17) << 16) : 0.f;
                av[0] = fmaf(v, __uint_as_float(gx[k].x << 16), av[0]);
                av[1] = fmaf(v, __uint_as_float(gx[k].x & 0xffff0000u), av[1]);
                av[2] = fmaf(v, __uint_as_float(gx[k].y << 16), av[2]);
                av[3] = fmaf(v, __uint_as_float(gx[k].y & 0xffff0000u), av[3]);
            }
#pragma unroll
            for (int k = 0; k < 8; ++k) edC[k] = edN[k];
        }
        // group g writes its row rr (16 lanes x 8B, conflict-free)
        int rr = j * 4 + g;
        uint p0 = (uint)bf16_rne(av[0]) | ((uint)bf16_rne(av[1]) << 16);
        uint p1 = (uint)bf16_rne(av[2]) | ((uint)bf16_rne(av[3]) << 16);
        *(uint2*)(xw + rr * 72 + q * 4) = make_uint2(p0, p1);
    }
    __syncthreads();   // X tiles visible (cross-lane/cross-wave)

    // ---- dense: D(16x64) = X @ W^T, 2 K-steps x 4 N-tiles ----
    f32x4 ac0 = {0.f, 0.f, 0.f, 0.f}, ac1 = ac0, ac2 = ac0, ac3 = ac0;
#pragma unroll
    for (int ks = 0; ks < 2; ++ks) {
        bf16x8 af = *(const bf16x8*)(xw + q * 72 + g * 8 + ks * 32);
        bf16x8 b0 = *(const bf16x8*)(wt + (q +  0) * 72 + g * 8 + ks * 32);
        bf16x8 b1 = *(const bf16x8*)(wt + (q + 16) * 72 + g * 8 + ks * 32);
        bf16x8 b2 = *(const bf16x8*)(wt + (q + 32) * 72 + g * 8 + ks * 32);
        bf16x8 b3 = *(const bf16x8*)(wt + (q + 48) * 72 + g * 8 + ks * 32);
        ac0 = __builtin_amdgcn_mfma_f32_16x16x32_bf16(af, b0, ac0, 0, 0, 0);
        ac1 = __builtin_amdgcn_mfma_f32_16x16x32_bf16(af, b1, ac1, 0, 0, 0);
        ac2 = __builtin_amdgcn_mfma_f32_16x16x32_bf16(af, b2, ac2, 0, 0, 0);
        ac3 = __builtin_amdgcn_mfma_f32_16x16x32_bf16(af, b3, ac3, 0, 0, 0);
    }

    // ---- bias + leaky_relu + L2 norm + store (non-temporal: no reuse) ----
    // lane holds D[row=g*4+r][col=q+16t] for t,r in 0..3
    float dv[4][4];
    float ss[4] = {0.f, 0.f, 0.f, 0.f};
#pragma unroll
    for (int t = 0; t < 4; ++t) {
        f32x4 a = (t == 0) ? ac0 : (t == 1) ? ac1 : (t == 2) ? ac2 : ac3;
#pragma unroll
        for (int r = 0; r < 4; ++r) {
            float d = a[r] + bias[t];
            d = (d > 0.f) ? d : 0.01f * d;
            dv[t][r] = d;
            ss[r] = fmaf(d, d, ss[r]);
        }
    }
#pragma unroll
    for (int r = 0; r < 4; ++r) {
        float s2 = ss[r];
        s2 += __shfl_xor(s2, 1);
        s2 += __shfl_xor(s2, 2);
        s2 += __shfl_xor(s2, 4);
        s2 += __shfl_xor(s2, 8);
        float scl = 1.0f / fmaxf(sqrtf(s2), 1e-12f);
        int orow = rowW + g * 4 + r;
        if (orow < n) {
#pragma unroll
            for (int t = 0; t < 4; ++t) {
                float outv = dv[t][r] * scl;
                size_t cidx = (size_t)orow * EMB + 16 * t + q;
                if (yb) __builtin_nontemporal_store(bf16_rne(outv), yb + cidx);
                else    __builtin_nontemporal_store(outv, yf + cidx);
            }
        }
    }
}

// ---------------- launch ----------------

extern "C" void kernel_launch(void* const* d_in, const int* in_sizes, int n_in,
                              void* d_out, int out_size, void* d_ws, size_t ws_size,
                              hipStream_t stream) {
    const float* user_emb = (const float*)d_in[0];
    const float* item_emb = (const float*)d_in[1];
    const float* Wu0 = (const float*)d_in[2];
    const float* bu0 = (const float*)d_in[3];
    const float* Wu1 = (const float*)d_in[4];
    const float* bu1 = (const float*)d_in[5];
    const float* Wi0 = (const float*)d_in[6];
    const float* bi0 = (const float*)d_in[7];
    const float* Wi1 = (const float*)d_in[8];
    const float* bi1 = (const float*)d_in[9];
    const int*   u_rows = (const int*)d_in[10];
    const int*   u_cols = (const int*)d_in[11];
    const float* u_vals = (const float*)d_in[12];
    const int*   i_rows = (const int*)d_in[13];
    const int*   i_cols = (const int*)d_in[14];
    const float* i_vals = (const float*)d_in[15];

    const int nu = in_sizes[0] / EMB;
    const int ni = in_sizes[1] / EMB;
    const int eu = in_sizes[10];
    const int ei = in_sizes[13];

    const int BU = 512, BI = 256;
    const int RPBU = (nu + BU - 1) / BU;   // 196
    const int RPBI = (ni + BI - 1) / BI;   // 196

    float* out_u = (float*)d_out;
    float* out_i = out_u + (size_t)nu * EMB;

    // workspace carve (256B aligned)
    size_t o = 0;
    char* wsb = (char*)d_ws;
    auto carve = [&](size_t bytes) -> void* {
        void* p = wsb + o;
        o += (bytes + 255) & ~(size_t)255;
        return p;
    };
    ushort* xbu0 = (ushort*)carve((size_t)nu * EMB * 2);   // bf16 cast of user_emb
    ushort* xbi0 = (ushort*)carve((size_t)ni * EMB * 2);   // bf16 cast of item_emb
    int2* binnedU = (int2*)carve((size_t)BU * CAPB * 8);   // build-time records
    int2* binnedI = (int2*)carve((size_t)BI * CAPB * 8);
    uint* ccvpU = (uint*)carve((size_t)BU * CAPB * 4);     // packed 4B CSR records
    uint* ccvpI = (uint*)carve((size_t)BI * CAPB * 4);
    ushort* xbu1 = (ushort*)carve((size_t)nu * EMB * 2);   // layer-0 outputs (bf16)
    ushort* xbi1 = (ushort*)carve((size_t)ni * EMB * 2);
    int2* offseU = (int2*)carve((size_t)nu * 8);           // per-row (start,end)
    int2* offseI = (int2*)carve((size_t)ni * 8);
    ushort* wpkU0 = (ushort*)carve(4096 * 2);              // packed bf16 weights
    ushort* wpkI0 = (ushort*)carve(4096 * 2);
    ushort* wpkU1 = (ushort*)carve(4096 * 2);
    ushort* wpkI1 = (ushort*)carve(4096 * 2);
    int*  gcur  = (int*)carve((size_t)(BU + BI) * 16 * 4); // one memset covers both
    int*  gcurU = gcur;
    int*  gcurI = gcur + (size_t)BU * 16;
    (void)ws_size;

    // ---- CSR build via bucket sort + embedding cast + W pack, compacted launches ----
    hipMemsetAsync(gcur, 0, (size_t)(BU + BI) * 16 * 4, stream);
    {
        int nbU = (eu + CHUNK - 1) / CHUNK;
        int nbI = (ei + CHUNK - 1) / CHUNK;
        long n4u = (long)nu * EMB / 4, n4i = (long)ni * EMB / 4;
        int nbCast = (int)((n4u + n4i + 1023) / 1024);
        prep<<<nbU + nbI + nbCast + 4, 256, 0, stream>>>(
            u_rows, u_cols, u_vals, eu, BU, RPBU, gcurU, binnedU, nbU,
            i_rows, i_cols, i_vals, ei, BI, RPBI, gcurI, binnedI, nbI,
            (const float4*)user_emb, xbu0, n4u,
            (const float4*)item_emb, xbi0, n4i, nbCast,
            (const float4*)Wu0, wpkU0, (const float4*)Wi0, wpkI0,
            (const float4*)Wu1, wpkU1, (const float4*)Wi1, wpkI1);
    }
    finalize_csr<<<BU + BI, 256, 0, stream>>>(
        binnedU, gcurU, RPBU, nu, ccvpU, offseU, BU,
        binnedI, gcurI, RPBI, ni, ccvpI, offseI);

    // ---- 2 GCN layers, fused per layer; ping-pong bf16 buffers ----
    int ntU = (nu + 63) >> 6, ntI = (ni + 63) >> 6;
    // layer 0: bf16(emb) -> bf16 tmp
    spmm_mfma<<<ntU + ntI, 256, 0, stream>>>(
        offseU, ccvpU, xbu0, wpkU0, bu0, nullptr, xbu1, nu, ntU,
        offseI, ccvpI, xbi0, wpkI0, bi0, nullptr, xbi1, ni);
    // layer 1: bf16 tmp -> f32 out
    spmm_mfma<<<ntU + ntI, 256, 0, stream>>>(
        offseU, ccvpU, xbu1, wpkU1, bu1, out_u, nullptr, nu, ntU,
        offseI, ccvpI, xbi1, wpkI1, bi1, out_i, nullptr, ni);
}

// Round 19
// 158.605 us; speedup vs baseline: 1.1562x; 1.1562x over previous
//
#include <hip/hip_runtime.h>
#include <hip/hip_bf16.h>
#include <math.h>

#define EMB 64
#define CAPB 3584      // per-bucket slot capacity (mean 3125, sigma ~56 -> 8.2 sigma)
#define CHUNK 4096     // edges per bin block

typedef __attribute__((ext_vector_type(8))) short bf16x8;
typedef __attribute__((ext_vector_type(4))) float f32x4;

__device__ __forceinline__ ushort bf16_rne(float f) {
    uint u = __float_as_uint(f);
    return (ushort)((u + 0x7fffu + ((u >> 16) & 1u)) >> 16);
}

__device__ __forceinline__ uint bf16_pack2(float a, float b) {
    return (uint)bf16_rne(a) | ((uint)bf16_rne(b) << 16);
}

// ---------------- prep kernel: bin(U) | bin(I) | cast_bf16 | pack W ----------------
// gcur assumed zeroed (hipMemsetAsync). Record: int2(col | inrow<<17, f32val).
// Binned writes are LDS-staged in bucket-sorted order -> coalesced full-line runs.

__device__ __forceinline__ void bin_body(
    const int* __restrict__ rows, const int* __restrict__ cols,
    const float* __restrict__ vals, int nE, int B, int RPB,
    int* gcur, int2* __restrict__ binned, int blk,
    int* cnt, int* sstart, int* lbase, int2* rec, ushort* bkt) {
    int t = threadIdx.x;
    for (int i = t; i < B; i += 256) cnt[i] = 0;
    __syncthreads();
    int c0 = blk * CHUNK;
    int ntot = nE - c0; if (ntot > CHUNK) ntot = CHUNK;
    int bs[16];
#pragma unroll
    for (int j = 0; j < 16; ++j) {
        int idx = c0 + t + j * 256;
        int bsv = -1;
        if (idx < nE) {
            int row = rows[idx];
            int b = row / RPB;
            int inrow = row - b * RPB;
            int slot = atomicAdd(&cnt[b], 1);
            bsv = (b << 21) | (inrow << 13) | slot;   // b<512, inrow<256, slot<8192
        }
        bs[j] = bsv;
    }
    __syncthreads();
    // reserve global runs per bucket
    for (int i = t; i < B; i += 256) {
        int c = cnt[i];
        lbase[i] = c ? atomicAdd(&gcur[i * 16], c) : 0;
    }
    // exclusive scan of cnt -> sstart (wave 0, B/64 segments with carry)
    if (t < 64) {
        int carry = 0;
        int nseg = B >> 6;
        for (int seg = 0; seg < nseg; ++seg) {
            int i = seg * 64 + t;
            int v = cnt[i];
            int s = v;
#pragma unroll
            for (int d = 1; d < 64; d <<= 1) {
                int u2 = __shfl_up(s, d);
                if (t >= d) s += u2;
            }
            sstart[i] = carry + s - v;
            carry += __shfl(s, 63);
        }
    }
    __syncthreads();
    // stage records into LDS in bucket-sorted order
#pragma unroll
    for (int j = 0; j < 16; ++j) {
        int idx = c0 + t + j * 256;
        if (idx >= nE) continue;
        int bsv = bs[j];
        int b = bsv >> 21, inrow = (bsv >> 13) & 0xFF, slot = bsv & 0x1FFF;
        int col = cols[idx];
        float v = vals[idx];
        int li = sstart[b] + slot;
        rec[li] = make_int2(col | (inrow << 17), __float_as_int(v));
        bkt[li] = (ushort)b;
    }
    __syncthreads();
    // coalesced copy: consecutive i in a bucket -> consecutive global dest
    for (int i = t; i < ntot; i += 256) {
        int b = bkt[i];
        int pos = lbase[b] + (i - sstart[b]);
        if (pos < CAPB)
            binned[(size_t)b * CAPB + pos] = rec[i];
    }
}

__global__ __launch_bounds__(256) void prep(
    const int* __restrict__ u_rows, const int* __restrict__ u_cols,
    const float* __restrict__ u_vals, int eu, int BU, int RPBU,
    int* gcurU, int2* __restrict__ binnedU, int nbU,
    const int* __restrict__ i_rows, const int* __restrict__ i_cols,
    const float* __restrict__ i_vals, int ei, int BI, int RPBI,
    int* gcurI, int2* __restrict__ binnedI, int nbI,
    const float4* __restrict__ embU, ushort* __restrict__ xbU, long n4u,
    const float4* __restrict__ embI, ushort* __restrict__ xbI, long n4i,
    int nbCast,
    const float4* __restrict__ W0s, ushort* __restrict__ W0d,
    const float4* __restrict__ W1s, ushort* __restrict__ W1d,
    const float4* __restrict__ W2s, ushort* __restrict__ W2d,
    const float4* __restrict__ W3s, ushort* __restrict__ W3d) {
    __shared__ int2 rec[CHUNK];        // 32 KB
    __shared__ ushort bkt[CHUNK];      // 8 KB
    __shared__ int cnt[512];
    __shared__ int sstart[512];
    __shared__ int lbase[512];
    int b = blockIdx.x;
    if (b < nbU) {
        bin_body(u_rows, u_cols, u_vals, eu, BU, RPBU, gcurU, binnedU, b,
                 cnt, sstart, lbase, rec, bkt);
        return;
    }
    b -= nbU;
    if (b < nbI) {
        bin_body(i_rows, i_cols, i_vals, ei, BI, RPBI, gcurI, binnedI, b,
                 cnt, sstart, lbase, rec, bkt);
        return;
    }
    b -= nbI;
    if (b < nbCast) {
        // cast: 4 float4 per thread, strided
        long tot = n4u + n4i;
        long base = (long)b * 1024 + threadIdx.x;
#pragma unroll
        for (int k = 0; k < 4; ++k) {
            long i = base + k * 256;
            if (i >= tot) return;
            const float4* a; ushort* o; long j;
            if (i < n4u) { a = embU; o = xbU; j = i; }
            else { a = embI; o = xbI; j = i - n4u; }
            float4 v = a[j];
            ushort4 r;
            r.x = bf16_rne(v.x); r.y = bf16_rne(v.y); r.z = bf16_rne(v.z); r.w = bf16_rne(v.w);
            *(ushort4*)(o + j * 4) = r;
        }
        return;
    }
    b -= nbCast;
    // pack one 64x64 W matrix to bf16 (16 contiguous elems per thread)
    {
        const float4* src = (b == 0) ? W0s : (b == 1) ? W1s : (b == 2) ? W2s : W3s;
        ushort* dst = (b == 0) ? W0d : (b == 1) ? W1d : (b == 2) ? W2d : W3d;
        int t = threadIdx.x;
        float4 v0 = src[t * 4 + 0], v1 = src[t * 4 + 1];
        float4 v2 = src[t * 4 + 2], v3 = src[t * 4 + 3];
        uint4 o0, o1;
        o0.x = bf16_pack2(v0.x, v0.y); o0.y = bf16_pack2(v0.z, v0.w);
        o0.z = bf16_pack2(v1.x, v1.y); o0.w = bf16_pack2(v1.z, v1.w);
        o1.x = bf16_pack2(v2.x, v2.y); o1.y = bf16_pack2(v2.z, v2.w);
        o1.z = bf16_pack2(v3.x, v3.y); o1.w = bf16_pack2(v3.z, v3.w);
        ((uint4*)dst)[t * 2 + 0] = o0;
        ((uint4*)dst)[t * 2 + 1] = o1;
    }
}

// ---------------- finalize: bucket sort -> packed 4B CSR records ----------------
// One workgroup per bucket. Row-sorts its records and emits 4-byte packed records:
//   uint( col[16:0] | bf16_sans_sign(val)[31:17] )   (vals are >= 0)
// plus per-row int2(start,end) offsets (uint indices into ccvp).

__global__ __launch_bounds__(256) void finalize_csr(
    const int2* __restrict__ binnedU, const int* __restrict__ gcurU, int RPBU, int nu,
    uint* __restrict__ ccvpU, int2* __restrict__ offseU, int BU,
    const int2* __restrict__ binnedI, const int* __restrict__ gcurI, int RPBI, int ni,
    uint* __restrict__ ccvpI, int2* __restrict__ offseI) {
    __shared__ int2 rec[CAPB];
    __shared__ int cnt_r[256];
    __shared__ int excl[257];
    __shared__ int curs[256];
    int b = blockIdx.x;
    const int2* binned; const int* gcur; int RPB; int n; uint* ccvp; int2* offse;
    if (b < BU) {
        binned = binnedU; gcur = gcurU; RPB = RPBU; n = nu; ccvp = ccvpU; offse = offseU;
    } else {
        b -= BU;
        binned = binnedI; gcur = gcurI; RPB = RPBI; n = ni; ccvp = ccvpI; offse = offseI;
    }
    int t = threadIdx.x;
    int r0 = b * RPB;
    int nrows = n - r0; if (nrows > RPB) nrows = RPB;
    if (nrows <= 0) return;
    int cnt = gcur[b * 16];
    if (cnt > CAPB) cnt = CAPB;
    const int2* src = binned + (size_t)b * CAPB;
    int B0 = b * CAPB;
    cnt_r[t] = 0;
    __syncthreads();
    for (int p = t; p < cnt; p += 256) {
        int2 r = src[p];
        rec[p] = r;
        atomicAdd(&cnt_r[(r.x >> 17) & 0xFF], 1);
    }
    __syncthreads();
    // exclusive scan of 256 counters: wave 0, 4 segments of 64 with carry
    if (t < 64) {
        int carry = 0;
#pragma unroll
        for (int seg = 0; seg < 4; ++seg) {
            int i = seg * 64 + t;
            int v = cnt_r[i];
            int s = v;
#pragma unroll
            for (int d = 1; d < 64; d <<= 1) {
                int u2 = __shfl_up(s, d);
                if (t >= d) s += u2;
            }
            excl[i] = carry + s - v;
            carry += __shfl(s, 63);
        }
        if (t == 0) excl[256] = carry;
    }
    __syncthreads();
    curs[t] = excl[t];
    if (t < nrows) offse[r0 + t] = make_int2(B0 + excl[t], B0 + excl[t + 1]);
    __syncthreads();
    for (int p = t; p < cnt; p += 256) {
        int2 r = rec[p];
        int inrow = (r.x >> 17) & 0xFF;
        int slot = atomicAdd(&curs[inrow], 1);
        float v = __int_as_float(r.y);                     // v >= 0
        uint v15 = ((uint)bf16_rne(v)) & 0x7FFFu;          // bf16 without sign bit
        ccvp[B0 + slot] = (uint)(r.x & 0x1FFFF) | (v15 << 17);
    }
}

// ---------------- fused SPMM + MFMA dense + leaky_relu + L2 norm ----------------
// ROUND-17 STATE (best verified: 54.3 us/layer). r18's non-temporal hints
// REGRESSED (-23%): the sequential record stream benefits from normal L2 line
// reuse (16 records/64B line); nt loads forfeit it and nt stores de-coalesce.
// ONE 64-row tile per block. Block = 4 waves; wave owns 16 rows in 4 passes of
// 4 rows; 16-lane group owns ONE row per pass, 8-deep edge batch + cross-batch
// record prefetch. Edge record 4B packed: col[16:0] | bf16_sans_sign(val)[31:17].
// W pre-packed bf16 in global. Dense: X(16x64)@W^T via 8x mfma_f32_16x16x32_bf16.
// C/D layout (verified): col=lane&15, row=(lane>>4)*4+reg. Norm: shfl_xor butterfly.
// x and y MUST be distinct buffers.

__global__ __launch_bounds__(256, 4) void spmm_mfma(
    const int2* __restrict__ offseU, const uint* __restrict__ ccvU,
    const ushort* __restrict__ xu, const ushort* __restrict__ Wu, const float* __restrict__ bu,
    float* __restrict__ yfu, ushort* __restrict__ ybu, int nu, int ntU,
    const int2* __restrict__ offseI, const uint* __restrict__ ccvI,
    const ushort* __restrict__ xi, const ushort* __restrict__ Wi, const float* __restrict__ bi,
    float* __restrict__ yfi, ushort* __restrict__ ybi, int ni) {
    __shared__ ushort wt[64 * 72];       // W row-major bf16, rows padded to 72
    __shared__ ushort xt[4 * 16 * 72];   // per-wave X tiles
    int tid = threadIdx.x;
    int lane = tid & 63, wid = tid >> 6;
    int q = lane & 15, g = lane >> 4;
    int tile = blockIdx.x;
    const int2* offse; const uint* ccv; const ushort* x; const ushort* W; const float* bv;
    float* yf; ushort* yb; int n;
    if (tile < ntU) {
        offse = offseU; ccv = ccvU; x = xu; W = Wu; bv = bu; yf = yfu; yb = ybu; n = nu;
    } else {
        tile -= ntU;
        offse = offseI; ccv = ccvI; x = xi; W = Wi; bv = bi; yf = yfi; yb = ybi; n = ni;
    }
    // stage W: thread t copies elements [t*16, t*16+16) -> row r=t/4, col (t%4)*16
    {
        int r = tid >> 2, c = (tid & 3) * 16;
        uint4 v0 = ((const uint4*)W)[tid * 2 + 0];
        uint4 v1 = ((const uint4*)W)[tid * 2 + 1];
        *(uint4*)(wt + r * 72 + c) = v0;
        *(uint4*)(wt + r * 72 + c + 8) = v1;
    }
    float bias[4];
#pragma unroll
    for (int t = 0; t < 4; ++t) bias[t] = bv[16 * t + q];
    __syncthreads();

    const uint2* xv2 = (const uint2*)x;
    ushort* xw = xt + wid * (16 * 72);
    int rowW = (tile << 6) + wid * 16;   // wave's first row

    // ---- preload the wave's 16 rows' offse: one coalesced 128B load ----
    int2 se = make_int2(0, 0);
    {
        int r16 = rowW + lane;
        if (lane < 16 && r16 < n) se = offse[r16];
    }
    int Sa[4], Ea[4];
#pragma unroll
    for (int j = 0; j < 4; ++j) {
        Sa[j] = __shfl(se.x, j * 4 + g);
        Ea[j] = __shfl(se.y, j * 4 + g);
    }

    // ---- pipelined gather: prefetch next batch's records during current gathers ----
    uint edC[8], edN[8];
    {   // prologue: records for (row 0, first batch)
        int sn = Sa[0], en = Ea[0];
        int safe = (en > sn) ? en - 1 : 0;
#pragma unroll
        for (int k = 0; k < 8; ++k) {
            int ii = sn + k;
            edC[k] = ccv[(ii < en) ? ii : safe];
        }
    }
#pragma unroll
    for (int j = 0; j < 4; ++j) {
        int s = Sa[j], e = Ea[j];
        int sN = (j < 3) ? Sa[j + 1] : 0;
        int eN = (j < 3) ? Ea[j + 1] : 0;
        float av[4] = {0.f, 0.f, 0.f, 0.f};
        int nb = (e - s + 7) >> 3; if (nb < 1) nb = 1;
        int p = s;
        for (int b = 0; b < nb; ++b, p += 8) {
            bool lastb = (b + 1 >= nb);
            int pn = lastb ? sN : (p + 8);
            int en = lastb ? eN : e;
            int sn = lastb ? sN : s;
            // gathers for current batch (records already resident)
            uint2 gx[8];
#pragma unroll
            for (int k = 0; k < 8; ++k)
                gx[k] = xv2[(size_t)(edC[k] & 0x1FFFFu) * 16 + q];
            // prefetch next batch's records (independent of gathers)
            int safeN = (en > sn) ? en - 1 : 0;
#pragma unroll
            for (int k = 0; k < 8; ++k) {
                int ii = pn + k;
                edN[k] = ccv[(ii < en) ? ii : safeN];
            }
            // accumulate
#pragma unroll
            for (int k = 0; k < 8; ++k) {
                float v = (p + k < e) ? __uint_as_float((edC[k] >> 17) << 16) : 0.f;
                av[0] = fmaf(v, __uint_as_float(gx[k].x << 16), av[0]);
                av[1] = fmaf(v, __uint_as_float(gx[k].x & 0xffff0000u), av[1]);
                av[2] = fmaf(v, __uint_as_float(gx[k].y << 16), av[2]);
                av[3] = fmaf(v, __uint_as_float(gx[k].y & 0xffff0000u), av[3]);
            }
#pragma unroll
            for (int k = 0; k < 8; ++k) edC[k] = edN[k];
        }
        // group g writes its row rr (16 lanes x 8B, conflict-free)
        int rr = j * 4 + g;
        uint p0 = (uint)bf16_rne(av[0]) | ((uint)bf16_rne(av[1]) << 16);
        uint p1 = (uint)bf16_rne(av[2]) | ((uint)bf16_rne(av[3]) << 16);
        *(uint2*)(xw + rr * 72 + q * 4) = make_uint2(p0, p1);
    }
    __syncthreads();   // X tiles visible (cross-lane/cross-wave)

    // ---- dense: D(16x64) = X @ W^T, 2 K-steps x 4 N-tiles ----
    f32x4 ac0 = {0.f, 0.f, 0.f, 0.f}, ac1 = ac0, ac2 = ac0, ac3 = ac0;
#pragma unroll
    for (int ks = 0; ks < 2; ++ks) {
        bf16x8 af = *(const bf16x8*)(xw + q * 72 + g * 8 + ks * 32);
        bf16x8 b0 = *(const bf16x8*)(wt + (q +  0) * 72 + g * 8 + ks * 32);
        bf16x8 b1 = *(const bf16x8*)(wt + (q + 16) * 72 + g * 8 + ks * 32);
        bf16x8 b2 = *(const bf16x8*)(wt + (q + 32) * 72 + g * 8 + ks * 32);
        bf16x8 b3 = *(const bf16x8*)(wt + (q + 48) * 72 + g * 8 + ks * 32);
        ac0 = __builtin_amdgcn_mfma_f32_16x16x32_bf16(af, b0, ac0, 0, 0, 0);
        ac1 = __builtin_amdgcn_mfma_f32_16x16x32_bf16(af, b1, ac1, 0, 0, 0);
        ac2 = __builtin_amdgcn_mfma_f32_16x16x32_bf16(af, b2, ac2, 0, 0, 0);
        ac3 = __builtin_amdgcn_mfma_f32_16x16x32_bf16(af, b3, ac3, 0, 0, 0);
    }

    // ---- bias + leaky_relu + L2 norm + store ----
    // lane holds D[row=g*4+r][col=q+16t] for t,r in 0..3
    float dv[4][4];
    float ss[4] = {0.f, 0.f, 0.f, 0.f};
#pragma unroll
    for (int t = 0; t < 4; ++t) {
        f32x4 a = (t == 0) ? ac0 : (t == 1) ? ac1 : (t == 2) ? ac2 : ac3;
#pragma unroll
        for (int r = 0; r < 4; ++r) {
            float d = a[r] + bias[t];
            d = (d > 0.f) ? d : 0.01f * d;
            dv[t][r] = d;
            ss[r] = fmaf(d, d, ss[r]);
        }
    }
#pragma unroll
    for (int r = 0; r < 4; ++r) {
        float s2 = ss[r];
        s2 += __shfl_xor(s2, 1);
        s2 += __shfl_xor(s2, 2);
        s2 += __shfl_xor(s2, 4);
        s2 += __shfl_xor(s2, 8);
        float scl = 1.0f / fmaxf(sqrtf(s2), 1e-12f);
        int orow = rowW + g * 4 + r;
        if (orow < n) {
#pragma unroll
            for (int t = 0; t < 4; ++t) {
                float outv = dv[t][r] * scl;
                size_t cidx = (size_t)orow * EMB + 16 * t + q;
                if (yb) yb[cidx] = bf16_rne(outv);
                else    yf[cidx] = outv;
            }
        }
    }
}

// ---------------- launch ----------------

extern "C" void kernel_launch(void* const* d_in, const int* in_sizes, int n_in,
                              void* d_out, int out_size, void* d_ws, size_t ws_size,
                              hipStream_t stream) {
    const float* user_emb = (const float*)d_in[0];
    const float* item_emb = (const float*)d_in[1];
    const float* Wu0 = (const float*)d_in[2];
    const float* bu0 = (const float*)d_in[3];
    const float* Wu1 = (const float*)d_in[4];
    const float* bu1 = (const float*)d_in[5];
    const float* Wi0 = (const float*)d_in[6];
    const float* bi0 = (const float*)d_in[7];
    const float* Wi1 = (const float*)d_in[8];
    const float* bi1 = (const float*)d_in[9];
    const int*   u_rows = (const int*)d_in[10];
    const int*   u_cols = (const int*)d_in[11];
    const float* u_vals = (const float*)d_in[12];
    const int*   i_rows = (const int*)d_in[13];
    const int*   i_cols = (const int*)d_in[14];
    const float* i_vals = (const float*)d_in[15];

    const int nu = in_sizes[0] / EMB;
    const int ni = in_sizes[1] / EMB;
    const int eu = in_sizes[10];
    const int ei = in_sizes[13];

    const int BU = 512, BI = 256;
    const int RPBU = (nu + BU - 1) / BU;   // 196
    const int RPBI = (ni + BI - 1) / BI;   // 196

    float* out_u = (float*)d_out;
    float* out_i = out_u + (size_t)nu * EMB;

    // workspace carve (256B aligned)
    size_t o = 0;
    char* wsb = (char*)d_ws;
    auto carve = [&](size_t bytes) -> void* {
        void* p = wsb + o;
        o += (bytes + 255) & ~(size_t)255;
        return p;
    };
    ushort* xbu0 = (ushort*)carve((size_t)nu * EMB * 2);   // bf16 cast of user_emb
    ushort* xbi0 = (ushort*)carve((size_t)ni * EMB * 2);   // bf16 cast of item_emb
    int2* binnedU = (int2*)carve((size_t)BU * CAPB * 8);   // build-time records
    int2* binnedI = (int2*)carve((size_t)BI * CAPB * 8);
    uint* ccvpU = (uint*)carve((size_t)BU * CAPB * 4);     // packed 4B CSR records
    uint* ccvpI = (uint*)carve((size_t)BI * CAPB * 4);
    ushort* xbu1 = (ushort*)carve((size_t)nu * EMB * 2);   // layer-0 outputs (bf16)
    ushort* xbi1 = (ushort*)carve((size_t)ni * EMB * 2);
    int2* offseU = (int2*)carve((size_t)nu * 8);           // per-row (start,end)
    int2* offseI = (int2*)carve((size_t)ni * 8);
    ushort* wpkU0 = (ushort*)carve(4096 * 2);              // packed bf16 weights
    ushort* wpkI0 = (ushort*)carve(4096 * 2);
    ushort* wpkU1 = (ushort*)carve(4096 * 2);
    ushort* wpkI1 = (ushort*)carve(4096 * 2);
    int*  gcur  = (int*)carve((size_t)(BU + BI) * 16 * 4); // one memset covers both
    int*  gcurU = gcur;
    int*  gcurI = gcur + (size_t)BU * 16;
    (void)ws_size;

    // ---- CSR build via bucket sort + embedding cast + W pack, compacted launches ----
    hipMemsetAsync(gcur, 0, (size_t)(BU + BI) * 16 * 4, stream);
    {
        int nbU = (eu + CHUNK - 1) / CHUNK;
        int nbI = (ei + CHUNK - 1) / CHUNK;
        long n4u = (long)nu * EMB / 4, n4i = (long)ni * EMB / 4;
        int nbCast = (int)((n4u + n4i + 1023) / 1024);
        prep<<<nbU + nbI + nbCast + 4, 256, 0, stream>>>(
            u_rows, u_cols, u_vals, eu, BU, RPBU, gcurU, binnedU, nbU,
            i_rows, i_cols, i_vals, ei, BI, RPBI, gcurI, binnedI, nbI,
            (const float4*)user_emb, xbu0, n4u,
            (const float4*)item_emb, xbi0, n4i, nbCast,
            (const float4*)Wu0, wpkU0, (const float4*)Wi0, wpkI0,
            (const float4*)Wu1, wpkU1, (const float4*)Wi1, wpkI1);
    }
    finalize_csr<<<BU + BI, 256, 0, stream>>>(
        binnedU, gcurU, RPBU, nu, ccvpU, offseU, BU,
        binnedI, gcurI, RPBI, ni, ccvpI, offseI);

    // ---- 2 GCN layers, fused per layer; ping-pong bf16 buffers ----
    int ntU = (nu + 63) >> 6, ntI = (ni + 63) >> 6;
    // layer 0: bf16(emb) -> bf16 tmp
    spmm_mfma<<<ntU + ntI, 256, 0, stream>>>(
        offseU, ccvpU, xbu0, wpkU0, bu0, nullptr, xbu1, nu, ntU,
        offseI, ccvpI, xbi0, wpkI0, bi0, nullptr, xbi1, ni);
    // layer 1: bf16 tmp -> f32 out
    spmm_mfma<<<ntU + ntI, 256, 0, stream>>>(
        offseU, ccvpU, xbu1, wpkU1, bu1, out_u, nullptr, nu, ntU,
        offseI, ccvpI, xbi1, wpkI1, bi1, out_i, nullptr, ni);
}